// Round 21
// baseline (126.721 us; speedup 1.0000x reference)
//
#include <hip/hip_runtime.h>
#include <hip/hip_bf16.h>
#include <math.h>

#define PI_F 3.14159265358979323846f

typedef float f32x4 __attribute__((ext_vector_type(4)));
typedef short bf16x8 __attribute__((ext_vector_type(8)));

__device__ __forceinline__ unsigned short bf_hi(float f) {
    return (unsigned short)(__float_as_uint(f) >> 16);     // truncate to bf16
}
__device__ __forceinline__ float from_bf(unsigned short h) {
    return __uint_as_float(((unsigned)h) << 16);
}

// ---------------------------------------------------------------------------
// Kernel 1 (merged): build U in LDS (4 waves x 16 basis states) then pack
// U and W1 into split-bf16 MFMA B-fragment layouts. One block, one launch,
// no global Umat round-trip. Gate math verified since R3; frag layouts
// verified R17 (U) / R18 (W1).
// ---------------------------------------------------------------------------
__global__ __launch_bounds__(256) void prep(
    const float* __restrict__ qw, const float* __restrict__ W1,
    unsigned short* __restrict__ Ubf, unsigned short* __restrict__ W1bf)
{
    __shared__ float Us[8192];               // Us[(k*64 + j)*2 + ri]

    const int tid = threadIdx.x;
    const int wv  = tid >> 6;
    const int l   = tid & 63;                // amplitude index k

    #pragma unroll 1
    for (int i = 0; i < 16; ++i) {
        const int b = wv * 16 + i;           // input basis state j

        float ar = (l == b) ? 1.0f : 0.0f;
        float ai = 0.0f;

        #pragma unroll
        for (int q = 0; q < 6; ++q) {
            const int mask = 1 << (5 - q);
            float th = 0.5f * qw[0 * 6 + q];
            float c = cosf(th), sn = sinf(th);
            float pr = __shfl_xor(ar, mask);
            float pi = __shfl_xor(ai, mask);
            float nr = c * ar + sn * pi;
            float ni = c * ai - sn * pr;
            ar = nr; ai = ni;
            th = 0.5f * qw[1 * 6 + q];
            c = cosf(th); sn = sinf(th);
            float zn = (l & mask) ? 1.0f : -1.0f;
            nr = c * ar - zn * sn * ai;
            ni = c * ai + zn * sn * ar;
            ar = nr; ai = ni;
        }

        #pragma unroll
        for (int q = 0; q < 6; ++q) {
            const int ctrl = q, tgt = (q + 1) % 6;
            const int cm = 1 << (5 - ctrl), tm = 1 << (5 - tgt);
            float pr = __shfl_xor(ar, tm);
            float pi = __shfl_xor(ai, tm);
            bool take = (l & cm) != 0;
            ar = take ? pr : ar;
            ai = take ? pi : ai;
        }

        #pragma unroll
        for (int q = 0; q < 6; ++q) {
            const int mask = 1 << (5 - q);
            float th = 0.5f * qw[2 * 6 + q];
            float c = cosf(th), sn = sinf(th);
            float pr = __shfl_xor(ar, mask);
            float pi = __shfl_xor(ai, mask);
            float sg = (l & mask) ? sn : -sn;
            float nr = c * ar + sg * pr;
            float ni = c * ai + sg * pi;
            ar = nr; ai = ni;
            th = 0.5f * qw[3 * 6 + q];
            c = cosf(th); sn = sinf(th);
            float zn = (l & mask) ? 1.0f : -1.0f;
            nr = c * ar - zn * sn * ai;
            ni = c * ai + zn * sn * ar;
            ar = nr; ai = ni;
        }

        #pragma unroll
        for (int q = 0; q < 6; q += 2) {
            const int cm = 1 << (5 - q), tm = 1 << (5 - (q + 1));
            float pr = __shfl_xor(ar, tm);
            float pi = __shfl_xor(ai, tm);
            bool take = (l & cm) != 0;
            ar = take ? pr : ar;
            ai = take ? pi : ai;
        }

        #pragma unroll
        for (int q = 0; q < 6; ++q) {
            const int mask = 1 << (5 - q);
            float th = 0.5f * qw[4 * 6 + q];
            float c = cosf(th), sn = sinf(th);
            float pr = __shfl_xor(ar, mask);
            float pi = __shfl_xor(ai, mask);
            float nr = c * ar + sn * pi;
            float ni = c * ai - sn * pr;
            ar = nr; ai = ni;
        }

        Us[(l * 64 + b) * 2 + 0] = ar;
        Us[(l * 64 + b) * 2 + 1] = ai;
    }

    __syncthreads();

    // ---- U frags: wave wv handles vf = wv*4 .. wv*4+3
    bf16x8* out8 = reinterpret_cast<bf16x8*>(Ubf);
    #pragma unroll
    for (int q = 0; q < 4; ++q) {
        const int vf = wv * 4 + q;           // vf = (ri*4+t)*2 + h
        const int h  = vf & 1;
        const int tt = (vf >> 1) & 3;
        const int ri = vf >> 3;
        bf16x8 vh, vl;
        #pragma unroll
        for (int e = 0; e < 8; ++e) {
            const int k = 16 * tt + (l & 15);
            const int j = h * 32 + (l >> 4) * 8 + e;
            float v = Us[(k * 64 + j) * 2 + ri];
            unsigned short hh = bf_hi(v);
            vh[e] = (short)hh;
            vl[e] = (short)bf_hi(v - from_bf(hh));
        }
        out8[(vf * 2 + 0) * 64 + l] = vh;
        out8[(vf * 2 + 1) * 64 + l] = vl;
    }

    // ---- W1 frags: wave wv handles kombo = wv*2, wv*2+1
    bf16x8* w8 = reinterpret_cast<bf16x8*>(W1bf);
    #pragma unroll
    for (int q = 0; q < 2; ++q) {
        const int kombo = wv * 2 + q;        // = ks*2 + nt
        const int ks = kombo >> 1;
        const int nt = kombo & 1;
        bf16x8 vh, vl;
        #pragma unroll
        for (int e = 0; e < 8; ++e) {
            float v = W1[(ks * 32 + (l >> 4) * 8 + e) * 32 + nt * 16 + (l & 15)];
            unsigned short hh = bf_hi(v);
            vh[e] = (short)hh;
            vl[e] = (short)bf_hi(v - from_bf(hh));
        }
        w8[(kombo * 2 + 0) * 64 + l] = vh;
        w8[(kombo * 2 + 1) * 64 + l] = vl;
    }
}

// ---------------------------------------------------------------------------
// Front MLP tail (layers 2,3 + half-product tables). Verified since R3.
// ---------------------------------------------------------------------------
__device__ __forceinline__ void front_tail(
    const float h1[32],
    const float* __restrict__ W2, const float* __restrict__ b2,
    const float* __restrict__ W3, const float* __restrict__ b3,
    float lo[8], float hi[8])
{
    float h2[16];
    #pragma unroll
    for (int o = 0; o < 16; ++o) h2[o] = b2[o];
    #pragma unroll
    for (int j = 0; j < 32; ++j) {
        #pragma unroll
        for (int o = 0; o < 16; ++o) h2[o] = fmaf(h1[j], W2[j * 16 + o], h2[o]);
    }
    #pragma unroll
    for (int o = 0; o < 16; ++o) h2[o] = fmaxf(h2[o], 0.0f);

    float cq[6], sq[6];
    #pragma unroll
    for (int q = 0; q < 6; ++q) {
        float t = b3[q];
        #pragma unroll
        for (int j = 0; j < 16; ++j) t = fmaf(h2[j], W3[j * 6 + q], t);
        t = tanhf(t);
        t = fminf(1.0f, fmaxf(-1.0f, t));
        float half = t * (0.5f * PI_F);
        sq[q] = sinf(half);
        cq[q] = cosf(half);
    }

    {
        float f3[2] = {cq[3], sq[3]};
        float f4[2] = {cq[4], sq[4]};
        float f5[2] = {cq[5], sq[5]};
        #pragma unroll
        for (int m = 0; m < 8; ++m)
            lo[m] = f3[(m >> 2) & 1] * f4[(m >> 1) & 1] * f5[m & 1];
        float f0[2] = {cq[0], sq[0]};
        float f1[2] = {cq[1], sq[1]};
        float f2[2] = {cq[2], sq[2]};
        #pragma unroll
        for (int m = 0; m < 8; ++m)
            hi[m] = f0[(m >> 2) & 1] * f1[(m >> 1) & 1] * f2[m & 1];
    }
}

// ---------------------------------------------------------------------------
// Split kernel A (R20, verified): front MLP, MFMA + coalesced LDS staging.
// ---------------------------------------------------------------------------
__global__ __launch_bounds__(256) void front_mfma(
    const float* __restrict__ x,
    const unsigned short* __restrict__ W1bf, const float* __restrict__ b1,
    const float* __restrict__ W2, const float* __restrict__ b2,
    const float* __restrict__ W3, const float* __restrict__ b3,
    float* __restrict__ tab, int B)
{
    __shared__ float smem[256 * 36];         // 36864 B, reused for h1 (stride 33)

    const int tid  = threadIdx.x;
    const int wv   = tid >> 6;
    const int lane = tid & 63;
    const int g    = lane >> 4;
    const int c    = lane & 15;
    const long blk = (long)blockIdx.x * 256;

    const f32x4* xg = reinterpret_cast<const f32x4*>(x);
    const bf16x8* Wb = reinterpret_cast<const bf16x8*>(W1bf);

    f32x4 acc0[4], acc1[4];
    #pragma unroll
    for (int mt = 0; mt < 4; ++mt) { acc0[mt] = (f32x4)0.0f; acc1[mt] = (f32x4)0.0f; }

    #pragma unroll 1
    for (int ks = 0; ks < 4; ++ks) {
        #pragma unroll
        for (int i = 0; i < 8; ++i) {
            const int flat = i * 256 + tid;
            const int row = flat >> 3;
            const int c4  = flat & 7;
            long srow = blk + row;
            if (srow >= B) srow = B - 1;
            f32x4 v = __builtin_nontemporal_load(&xg[(size_t)srow * 32 + ks * 8 + c4]);
            *reinterpret_cast<f32x4*>(&smem[row * 36 + c4 * 4]) = v;
        }
        __syncthreads();

        bf16x8 B0h = Wb[((ks * 2 + 0) * 2 + 0) * 64 + lane];
        bf16x8 B0l = Wb[((ks * 2 + 0) * 2 + 1) * 64 + lane];
        bf16x8 B1h = Wb[((ks * 2 + 1) * 2 + 0) * 64 + lane];
        bf16x8 B1l = Wb[((ks * 2 + 1) * 2 + 1) * 64 + lane];

        #pragma unroll
        for (int mt = 0; mt < 4; ++mt) {
            const int row = wv * 64 + mt * 16 + c;
            f32x4 xa = *reinterpret_cast<const f32x4*>(&smem[row * 36 + g * 8]);
            f32x4 xb = *reinterpret_cast<const f32x4*>(&smem[row * 36 + g * 8 + 4]);

            bf16x8 Ah, Al;
            #pragma unroll
            for (int e = 0; e < 4; ++e) {
                unsigned short hh = bf_hi(xa[e]);
                Ah[e] = (short)hh;
                Al[e] = (short)bf_hi(xa[e] - from_bf(hh));
            }
            #pragma unroll
            for (int e = 0; e < 4; ++e) {
                unsigned short hh = bf_hi(xb[e]);
                Ah[4 + e] = (short)hh;
                Al[4 + e] = (short)bf_hi(xb[e] - from_bf(hh));
            }

            acc0[mt] = __builtin_amdgcn_mfma_f32_16x16x32_bf16(Ah, B0h, acc0[mt], 0, 0, 0);
            acc0[mt] = __builtin_amdgcn_mfma_f32_16x16x32_bf16(Al, B0h, acc0[mt], 0, 0, 0);
            acc0[mt] = __builtin_amdgcn_mfma_f32_16x16x32_bf16(Ah, B0l, acc0[mt], 0, 0, 0);
            acc1[mt] = __builtin_amdgcn_mfma_f32_16x16x32_bf16(Ah, B1h, acc1[mt], 0, 0, 0);
            acc1[mt] = __builtin_amdgcn_mfma_f32_16x16x32_bf16(Al, B1h, acc1[mt], 0, 0, 0);
            acc1[mt] = __builtin_amdgcn_mfma_f32_16x16x32_bf16(Ah, B1l, acc1[mt], 0, 0, 0);
        }
        __syncthreads();
    }

    #pragma unroll
    for (int mt = 0; mt < 4; ++mt) {
        #pragma unroll
        for (int r = 0; r < 4; ++r) {
            smem[(wv * 64 + mt * 16 + g * 4 + r) * 33 + c]      = acc0[mt][r];
            smem[(wv * 64 + mt * 16 + g * 4 + r) * 33 + 16 + c] = acc1[mt][r];
        }
    }

    __syncthreads();

    const int s = (int)(blk + tid);
    float h1[32];
    #pragma unroll
    for (int o = 0; o < 32; ++o) h1[o] = fmaxf(smem[tid * 33 + o] + b1[o], 0.0f);

    float lo[8], hi[8];
    front_tail(h1, W2, b2, W3, b3, lo, hi);

    if (s < B) {
        #pragma unroll
        for (int i = 0; i < 8; ++i)
            __builtin_nontemporal_store(lo[i], &tab[(size_t)i * B + s]);
        #pragma unroll
        for (int i = 0; i < 8; ++i)
            __builtin_nontemporal_store(hi[i], &tab[(size_t)(8 + i) * B + s]);
    }
}

// ---------------------------------------------------------------------------
// Split kernel B: MFMA GEMV, 256 samples per block (mt-loop over 4 M-tiles
// per wave — R19 phase-3 code, proven correct), then back MLP on ALL 256
// threads (one sample each; was 1/4-idle on the 64-sample version).
// qlds stride 9 (odd) -> conflict-free back-MLP reads.
// ---------------------------------------------------------------------------
__global__ __launch_bounds__(256) void gemv_mfma(
    const float* __restrict__ tab,
    const unsigned short* __restrict__ Ubf,
    const float* __restrict__ W4, const float* __restrict__ b4,
    const float* __restrict__ W5, const float* __restrict__ b5,
    float* __restrict__ out, int B)
{
    __shared__ float qlds[256 * 9];

    const int tid  = threadIdx.x;
    const int wv   = tid >> 6;
    const int lane = tid & 63;
    const int g    = lane >> 4;
    const int c    = lane & 15;
    const long blk = (long)blockIdx.x * 256;

    const bf16x8* Ub = reinterpret_cast<const bf16x8*>(Ubf);

    #pragma unroll 1
    for (int mt = 0; mt < 4; ++mt) {
        const int s    = (int)(blk + wv * 64 + mt * 16 + c);
        const int s_ld = (s < B) ? s : (B - 1);

        float tl[8], th[8];
        #pragma unroll
        for (int i = 0; i < 8; ++i)
            tl[i] = __builtin_nontemporal_load(&tab[(size_t)i * B + s_ld]);
        #pragma unroll
        for (int i = 0; i < 8; ++i)
            th[i] = __builtin_nontemporal_load(&tab[(size_t)(8 + i) * B + s_ld]);

        float bh0 = (g == 0) ? th[0] : (g == 1) ? th[1] : (g == 2) ? th[2] : th[3];
        float bh1 = (g == 0) ? th[4] : (g == 1) ? th[5] : (g == 2) ? th[6] : th[7];

        bf16x8 Ah0, Al0, Ah1, Al1;
        #pragma unroll
        for (int e = 0; e < 8; ++e) {
            float p0 = bh0 * tl[e];
            unsigned short h0 = bf_hi(p0);
            Ah0[e] = (short)h0;
            Al0[e] = (short)bf_hi(p0 - from_bf(h0));
            float p1 = bh1 * tl[e];
            unsigned short h1 = bf_hi(p1);
            Ah1[e] = (short)h1;
            Al1[e] = (short)bf_hi(p1 - from_bf(h1));
        }

        f32x4 accre[4], accim[4];
        #pragma unroll
        for (int t = 0; t < 4; ++t) { accre[t] = (f32x4)0.0f; accim[t] = (f32x4)0.0f; }

        #pragma unroll
        for (int t = 0; t < 4; ++t) {
            bf16x8 B0h = Ub[(((0 * 4 + t) * 2 + 0) * 2 + 0) * 64 + lane];
            bf16x8 B0l = Ub[(((0 * 4 + t) * 2 + 0) * 2 + 1) * 64 + lane];
            bf16x8 B1h = Ub[(((0 * 4 + t) * 2 + 1) * 2 + 0) * 64 + lane];
            bf16x8 B1l = Ub[(((0 * 4 + t) * 2 + 1) * 2 + 1) * 64 + lane];
            accre[t] = __builtin_amdgcn_mfma_f32_16x16x32_bf16(Ah0, B0h, accre[t], 0, 0, 0);
            accre[t] = __builtin_amdgcn_mfma_f32_16x16x32_bf16(Al0, B0h, accre[t], 0, 0, 0);
            accre[t] = __builtin_amdgcn_mfma_f32_16x16x32_bf16(Ah0, B0l, accre[t], 0, 0, 0);
            accre[t] = __builtin_amdgcn_mfma_f32_16x16x32_bf16(Ah1, B1h, accre[t], 0, 0, 0);
            accre[t] = __builtin_amdgcn_mfma_f32_16x16x32_bf16(Al1, B1h, accre[t], 0, 0, 0);
            accre[t] = __builtin_amdgcn_mfma_f32_16x16x32_bf16(Ah1, B1l, accre[t], 0, 0, 0);
        }
        #pragma unroll
        for (int t = 0; t < 4; ++t) {
            bf16x8 B0h = Ub[(((1 * 4 + t) * 2 + 0) * 2 + 0) * 64 + lane];
            bf16x8 B0l = Ub[(((1 * 4 + t) * 2 + 0) * 2 + 1) * 64 + lane];
            bf16x8 B1h = Ub[(((1 * 4 + t) * 2 + 1) * 2 + 0) * 64 + lane];
            bf16x8 B1l = Ub[(((1 * 4 + t) * 2 + 1) * 2 + 1) * 64 + lane];
            accim[t] = __builtin_amdgcn_mfma_f32_16x16x32_bf16(Ah0, B0h, accim[t], 0, 0, 0);
            accim[t] = __builtin_amdgcn_mfma_f32_16x16x32_bf16(Al0, B0h, accim[t], 0, 0, 0);
            accim[t] = __builtin_amdgcn_mfma_f32_16x16x32_bf16(Ah0, B0l, accim[t], 0, 0, 0);
            accim[t] = __builtin_amdgcn_mfma_f32_16x16x32_bf16(Ah1, B1h, accim[t], 0, 0, 0);
            accim[t] = __builtin_amdgcn_mfma_f32_16x16x32_bf16(Al1, B1h, accim[t], 0, 0, 0);
            accim[t] = __builtin_amdgcn_mfma_f32_16x16x32_bf16(Ah1, B1l, accim[t], 0, 0, 0);
        }

        #pragma unroll
        for (int r = 0; r < 4; ++r) {
            float p0 = accre[0][r] * accre[0][r] + accim[0][r] * accim[0][r];
            float p1 = accre[1][r] * accre[1][r] + accim[1][r] * accim[1][r];
            float p2 = accre[2][r] * accre[2][r] + accim[2][r] * accim[2][r];
            float p3 = accre[3][r] * accre[3][r] + accim[3][r] * accim[3][r];

            float P0 = p0 + p1 + p2 + p3;
            float P1 = p0 + p1 - p2 - p3;
            float P2 = p0 - p1 + p2 - p3;

            float v = P0;
            #pragma unroll
            for (int st = 0; st < 4; ++st) {
                const int m = 1 << st;
                float prt = __shfl_xor(v, m);
                v = (lane & m) ? (prt - v) : (prt + v);
            }
            #pragma unroll
            for (int st = 0; st < 4; ++st) P1 += __shfl_xor(P1, 1 << st);
            #pragma unroll
            for (int st = 0; st < 4; ++st) P2 += __shfl_xor(P2, 1 << st);

            const int so = wv * 64 + mt * 16 + g * 4 + r;
            float* qrow = &qlds[so * 9];
            if (c == 0) { qrow[0] = P1; qrow[1] = P2; }
            if (c == 8) qrow[2] = v;
            if (c == 4) qrow[3] = v;
            if (c == 2) qrow[4] = v;
            if (c == 1) qrow[5] = v;
        }
    }

    __syncthreads();

    // ---- back MLP: all 256 threads, one sample each
    {
        const int so = (int)(blk + tid);
        const float* qrow = &qlds[tid * 9];
        float qv[6];
        #pragma unroll
        for (int i = 0; i < 6; ++i) qv[i] = qrow[i];

        float h4[16];
        #pragma unroll
        for (int o = 0; o < 16; ++o) h4[o] = b4[o];
        #pragma unroll
        for (int q = 0; q < 6; ++q) {
            #pragma unroll
            for (int o = 0; o < 16; ++o) h4[o] = fmaf(qv[q], W4[q * 16 + o], h4[o]);
        }
        #pragma unroll
        for (int o = 0; o < 16; ++o) h4[o] = fmaxf(h4[o], 0.0f);

        float o5[20];
        #pragma unroll
        for (int o = 0; o < 20; ++o) {
            float t = b5[o];
            #pragma unroll
            for (int j = 0; j < 16; ++j) t = fmaf(h4[j], W5[j * 20 + o], t);
            o5[o] = t;
        }

        if (so < B) {
            f32x4* outv = reinterpret_cast<f32x4*>(out + (size_t)so * 20);
            #pragma unroll
            for (int i = 0; i < 5; ++i) {
                f32x4 v = {o5[4 * i], o5[4 * i + 1], o5[4 * i + 2], o5[4 * i + 3]};
                __builtin_nontemporal_store(v, &outv[i]);
            }
        }
    }
}

// ---------------------------------------------------------------------------
extern "C" void kernel_launch(void* const* d_in, const int* in_sizes, int n_in,
                              void* d_out, int out_size, void* d_ws, size_t ws_size,
                              hipStream_t stream) {
    const float* x  = (const float*)d_in[0];
    const float* W1 = (const float*)d_in[1];
    const float* b1 = (const float*)d_in[2];
    const float* W2 = (const float*)d_in[3];
    const float* b2 = (const float*)d_in[4];
    const float* W3 = (const float*)d_in[5];
    const float* b3 = (const float*)d_in[6];
    const float* qw = (const float*)d_in[7];
    const float* W4 = (const float*)d_in[8];
    const float* b4 = (const float*)d_in[9];
    const float* W5 = (const float*)d_in[10];
    const float* b5 = (const float*)d_in[11];
    float* out = (float*)d_out;

    const int B = in_sizes[0] / 128;

    unsigned short* Ubf  = (unsigned short*)d_ws;          // 16384 ushort = 32 KB
    unsigned short* W1bf = Ubf + 16384;                    // 8192 ushort = 16 KB
    float* tab = (float*)(W1bf + 8192);                    // 16*B floats

    prep<<<1, 256, 0, stream>>>(qw, W1, Ubf, W1bf);
    front_mfma<<<(B + 255) / 256, 256, 0, stream>>>(
        x, W1bf, b1, W2, b2, W3, b3, tab, B);
    gemv_mfma<<<(B + 255) / 256, 256, 0, stream>>>(
        tab, Ubf, W4, b4, W5, b5, out, B);
}

// Round 22
// 97.328 us; speedup vs baseline: 1.3020x; 1.3020x over previous
//
#include <hip/hip_runtime.h>
#include <hip/hip_bf16.h>
#include <math.h>

#define PI_F 3.14159265358979323846f

typedef float f32x4 __attribute__((ext_vector_type(4)));
typedef short bf16x8 __attribute__((ext_vector_type(8)));

__device__ __forceinline__ unsigned short bf_hi(float f) {
    return (unsigned short)(__float_as_uint(f) >> 16);     // truncate to bf16
}
__device__ __forceinline__ float from_bf(unsigned short h) {
    return __uint_as_float(((unsigned)h) << 16);
}

// ---------------------------------------------------------------------------
// Kernel 1: build the fixed 64x64 complex unitary U. K-MAJOR layout:
// Umat[k*128 + j*2 + {0,1}] = {Re,Im} of U[k][j]. 64 parallel blocks.
// ---------------------------------------------------------------------------
__global__ __launch_bounds__(64) void build_u(const float* __restrict__ qw,
                                              float* __restrict__ Umat) {
    const int l = threadIdx.x;   // amplitude index k (0..63)
    const int b = blockIdx.x;    // input basis state j (0..63)

    float ar = (l == b) ? 1.0f : 0.0f;
    float ai = 0.0f;

    #pragma unroll
    for (int i = 0; i < 6; ++i) {
        const int mask = 1 << (5 - i);
        float th = 0.5f * qw[0 * 6 + i];
        float c = cosf(th), sn = sinf(th);
        float pr = __shfl_xor(ar, mask);
        float pi = __shfl_xor(ai, mask);
        float nr = c * ar + sn * pi;
        float ni = c * ai - sn * pr;
        ar = nr; ai = ni;
        th = 0.5f * qw[1 * 6 + i];
        c = cosf(th); sn = sinf(th);
        float zn = (l & mask) ? 1.0f : -1.0f;
        nr = c * ar - zn * sn * ai;
        ni = c * ai + zn * sn * ar;
        ar = nr; ai = ni;
    }

    #pragma unroll
    for (int i = 0; i < 6; ++i) {
        const int ctrl = i, tgt = (i + 1) % 6;
        const int cm = 1 << (5 - ctrl), tm = 1 << (5 - tgt);
        float pr = __shfl_xor(ar, tm);
        float pi = __shfl_xor(ai, tm);
        bool take = (l & cm) != 0;
        ar = take ? pr : ar;
        ai = take ? pi : ai;
    }

    #pragma unroll
    for (int i = 0; i < 6; ++i) {
        const int mask = 1 << (5 - i);
        float th = 0.5f * qw[2 * 6 + i];
        float c = cosf(th), sn = sinf(th);
        float pr = __shfl_xor(ar, mask);
        float pi = __shfl_xor(ai, mask);
        float sg = (l & mask) ? sn : -sn;
        float nr = c * ar + sg * pr;
        float ni = c * ai + sg * pi;
        ar = nr; ai = ni;
        th = 0.5f * qw[3 * 6 + i];
        c = cosf(th); sn = sinf(th);
        float zn = (l & mask) ? 1.0f : -1.0f;
        nr = c * ar - zn * sn * ai;
        ni = c * ai + zn * sn * ar;
        ar = nr; ai = ni;
    }

    #pragma unroll
    for (int i = 0; i < 6; i += 2) {
        const int cm = 1 << (5 - i), tm = 1 << (5 - (i + 1));
        float pr = __shfl_xor(ar, tm);
        float pi = __shfl_xor(ai, tm);
        bool take = (l & cm) != 0;
        ar = take ? pr : ar;
        ai = take ? pi : ai;
    }

    #pragma unroll
    for (int i = 0; i < 6; ++i) {
        const int mask = 1 << (5 - i);
        float th = 0.5f * qw[4 * 6 + i];
        float c = cosf(th), sn = sinf(th);
        float pr = __shfl_xor(ar, mask);
        float pi = __shfl_xor(ai, mask);
        float nr = c * ar + sn * pi;
        float ni = c * ai - sn * pr;
        ar = nr; ai = ni;
    }

    Umat[(l * 64 + b) * 2 + 0] = ar;   // k-major: row k=l, col j=b
    Umat[(l * 64 + b) * 2 + 1] = ai;
}

// ---------------------------------------------------------------------------
// Kernel 1b: pack U and W1 into split-bf16 MFMA B-fragment layout
// (both verified: U in R17, W1 in R18).
// ---------------------------------------------------------------------------
__global__ __launch_bounds__(64) void convert_all(
    const float* __restrict__ Umat, const float* __restrict__ W1,
    unsigned short* __restrict__ Ubf, unsigned short* __restrict__ W1bf)
{
    const int l = threadIdx.x;
    bf16x8* out8 = reinterpret_cast<bf16x8*>(Ubf);

    #pragma unroll
    for (int ri = 0; ri < 2; ++ri) {
        #pragma unroll
        for (int t = 0; t < 4; ++t) {
            #pragma unroll
            for (int h = 0; h < 2; ++h) {
                const int vf = (ri * 4 + t) * 2 + h;
                bf16x8 vh, vl;
                #pragma unroll
                for (int e = 0; e < 8; ++e) {
                    const int k = 16 * t + (l & 15);
                    const int j = h * 32 + (l >> 4) * 8 + e;
                    float v = Umat[k * 128 + j * 2 + ri];
                    unsigned short hh = bf_hi(v);
                    vh[e] = (short)hh;
                    vl[e] = (short)bf_hi(v - from_bf(hh));
                }
                out8[(vf * 2 + 0) * 64 + l] = vh;
                out8[(vf * 2 + 1) * 64 + l] = vl;
            }
        }
    }

    bf16x8* w8 = reinterpret_cast<bf16x8*>(W1bf);
    #pragma unroll
    for (int ks = 0; ks < 4; ++ks) {
        #pragma unroll
        for (int nt = 0; nt < 2; ++nt) {
            bf16x8 vh, vl;
            #pragma unroll
            for (int e = 0; e < 8; ++e) {
                float v = W1[(ks * 32 + (l >> 4) * 8 + e) * 32 + nt * 16 + (l & 15)];
                unsigned short hh = bf_hi(v);
                vh[e] = (short)hh;
                vl[e] = (short)bf_hi(v - from_bf(hh));
            }
            w8[((ks * 2 + nt) * 2 + 0) * 64 + l] = vh;
            w8[((ks * 2 + nt) * 2 + 1) * 64 + l] = vl;
        }
    }
}

// ---------------------------------------------------------------------------
// Front MLP tail (layers 2,3 + half-product tables). Verified since R3.
// ---------------------------------------------------------------------------
__device__ __forceinline__ void front_tail(
    const float h1[32],
    const float* __restrict__ W2, const float* __restrict__ b2,
    const float* __restrict__ W3, const float* __restrict__ b3,
    float lo[8], float hi[8])
{
    float h2[16];
    #pragma unroll
    for (int o = 0; o < 16; ++o) h2[o] = b2[o];
    #pragma unroll
    for (int j = 0; j < 32; ++j) {
        #pragma unroll
        for (int o = 0; o < 16; ++o) h2[o] = fmaf(h1[j], W2[j * 16 + o], h2[o]);
    }
    #pragma unroll
    for (int o = 0; o < 16; ++o) h2[o] = fmaxf(h2[o], 0.0f);

    float cq[6], sq[6];
    #pragma unroll
    for (int q = 0; q < 6; ++q) {
        float t = b3[q];
        #pragma unroll
        for (int j = 0; j < 16; ++j) t = fmaf(h2[j], W3[j * 6 + q], t);
        t = tanhf(t);
        t = fminf(1.0f, fmaxf(-1.0f, t));
        float half = t * (0.5f * PI_F);
        sq[q] = sinf(half);
        cq[q] = cosf(half);
    }

    {
        float f3[2] = {cq[3], sq[3]};
        float f4[2] = {cq[4], sq[4]};
        float f5[2] = {cq[5], sq[5]};
        #pragma unroll
        for (int m = 0; m < 8; ++m)
            lo[m] = f3[(m >> 2) & 1] * f4[(m >> 1) & 1] * f5[m & 1];
        float f0[2] = {cq[0], sq[0]};
        float f1[2] = {cq[1], sq[1]};
        float f2[2] = {cq[2], sq[2]};
        #pragma unroll
        for (int m = 0; m < 8; ++m)
            hi[m] = f0[(m >> 2) & 1] * f1[(m >> 1) & 1] * f2[m & 1];
    }
}

// ---------------------------------------------------------------------------
// Split kernel A (R20, verified): front MLP, MFMA + coalesced LDS staging.
// ---------------------------------------------------------------------------
__global__ __launch_bounds__(256) void front_mfma(
    const float* __restrict__ x,
    const unsigned short* __restrict__ W1bf, const float* __restrict__ b1,
    const float* __restrict__ W2, const float* __restrict__ b2,
    const float* __restrict__ W3, const float* __restrict__ b3,
    float* __restrict__ tab, int B)
{
    __shared__ float smem[256 * 36];         // 36864 B, reused for h1 (stride 33)

    const int tid  = threadIdx.x;
    const int wv   = tid >> 6;
    const int lane = tid & 63;
    const int g    = lane >> 4;
    const int c    = lane & 15;
    const long blk = (long)blockIdx.x * 256;

    const f32x4* xg = reinterpret_cast<const f32x4*>(x);
    const bf16x8* Wb = reinterpret_cast<const bf16x8*>(W1bf);

    f32x4 acc0[4], acc1[4];
    #pragma unroll
    for (int mt = 0; mt < 4; ++mt) { acc0[mt] = (f32x4)0.0f; acc1[mt] = (f32x4)0.0f; }

    #pragma unroll 1
    for (int ks = 0; ks < 4; ++ks) {
        #pragma unroll
        for (int i = 0; i < 8; ++i) {
            const int flat = i * 256 + tid;
            const int row = flat >> 3;
            const int c4  = flat & 7;
            long srow = blk + row;
            if (srow >= B) srow = B - 1;
            f32x4 v = __builtin_nontemporal_load(&xg[(size_t)srow * 32 + ks * 8 + c4]);
            *reinterpret_cast<f32x4*>(&smem[row * 36 + c4 * 4]) = v;
        }
        __syncthreads();

        bf16x8 B0h = Wb[((ks * 2 + 0) * 2 + 0) * 64 + lane];
        bf16x8 B0l = Wb[((ks * 2 + 0) * 2 + 1) * 64 + lane];
        bf16x8 B1h = Wb[((ks * 2 + 1) * 2 + 0) * 64 + lane];
        bf16x8 B1l = Wb[((ks * 2 + 1) * 2 + 1) * 64 + lane];

        #pragma unroll
        for (int mt = 0; mt < 4; ++mt) {
            const int row = wv * 64 + mt * 16 + c;
            f32x4 xa = *reinterpret_cast<const f32x4*>(&smem[row * 36 + g * 8]);
            f32x4 xb = *reinterpret_cast<const f32x4*>(&smem[row * 36 + g * 8 + 4]);

            bf16x8 Ah, Al;
            #pragma unroll
            for (int e = 0; e < 4; ++e) {
                unsigned short hh = bf_hi(xa[e]);
                Ah[e] = (short)hh;
                Al[e] = (short)bf_hi(xa[e] - from_bf(hh));
            }
            #pragma unroll
            for (int e = 0; e < 4; ++e) {
                unsigned short hh = bf_hi(xb[e]);
                Ah[4 + e] = (short)hh;
                Al[4 + e] = (short)bf_hi(xb[e] - from_bf(hh));
            }

            acc0[mt] = __builtin_amdgcn_mfma_f32_16x16x32_bf16(Ah, B0h, acc0[mt], 0, 0, 0);
            acc0[mt] = __builtin_amdgcn_mfma_f32_16x16x32_bf16(Al, B0h, acc0[mt], 0, 0, 0);
            acc0[mt] = __builtin_amdgcn_mfma_f32_16x16x32_bf16(Ah, B0l, acc0[mt], 0, 0, 0);
            acc1[mt] = __builtin_amdgcn_mfma_f32_16x16x32_bf16(Ah, B1h, acc1[mt], 0, 0, 0);
            acc1[mt] = __builtin_amdgcn_mfma_f32_16x16x32_bf16(Al, B1h, acc1[mt], 0, 0, 0);
            acc1[mt] = __builtin_amdgcn_mfma_f32_16x16x32_bf16(Ah, B1l, acc1[mt], 0, 0, 0);
        }
        __syncthreads();
    }

    #pragma unroll
    for (int mt = 0; mt < 4; ++mt) {
        #pragma unroll
        for (int r = 0; r < 4; ++r) {
            smem[(wv * 64 + mt * 16 + g * 4 + r) * 33 + c]      = acc0[mt][r];
            smem[(wv * 64 + mt * 16 + g * 4 + r) * 33 + 16 + c] = acc1[mt][r];
        }
    }

    __syncthreads();

    const int s = (int)(blk + tid);
    float h1[32];
    #pragma unroll
    for (int o = 0; o < 32; ++o) h1[o] = fmaxf(smem[tid * 33 + o] + b1[o], 0.0f);

    float lo[8], hi[8];
    front_tail(h1, W2, b2, W3, b3, lo, hi);

    if (s < B) {
        #pragma unroll
        for (int i = 0; i < 8; ++i)
            __builtin_nontemporal_store(lo[i], &tab[(size_t)i * B + s]);
        #pragma unroll
        for (int i = 0; i < 8; ++i)
            __builtin_nontemporal_store(hi[i], &tab[(size_t)(8 + i) * B + s]);
    }
}

// ---------------------------------------------------------------------------
// Split kernel B (R17/R18/R20, verified): straight-line MFMA GEMV, 64
// samples/block, epilogue + back MLP on threads 0..63 (waves 1-3 exit).
// ---------------------------------------------------------------------------
__global__ __launch_bounds__(256) void gemv_mfma(
    const float* __restrict__ tab,
    const unsigned short* __restrict__ Ubf,
    const float* __restrict__ W4, const float* __restrict__ b4,
    const float* __restrict__ W5, const float* __restrict__ b5,
    float* __restrict__ out, int B)
{
    __shared__ float qlds[64][8];

    const int tid  = threadIdx.x;
    const int wv   = tid >> 6;
    const int lane = tid & 63;
    const int g    = lane >> 4;
    const int c    = lane & 15;
    const long blk = (long)blockIdx.x * 64;
    const int s    = (int)(blk + wv * 16 + c);
    const int s_ld = (s < B) ? s : (B - 1);

    float tl[8], th[8];
    #pragma unroll
    for (int i = 0; i < 8; ++i)
        tl[i] = __builtin_nontemporal_load(&tab[(size_t)i * B + s_ld]);
    #pragma unroll
    for (int i = 0; i < 8; ++i)
        th[i] = __builtin_nontemporal_load(&tab[(size_t)(8 + i) * B + s_ld]);

    float bh0 = (g == 0) ? th[0] : (g == 1) ? th[1] : (g == 2) ? th[2] : th[3];
    float bh1 = (g == 0) ? th[4] : (g == 1) ? th[5] : (g == 2) ? th[6] : th[7];

    bf16x8 Ah0, Al0, Ah1, Al1;
    #pragma unroll
    for (int e = 0; e < 8; ++e) {
        float p0 = bh0 * tl[e];
        unsigned short h0 = bf_hi(p0);
        Ah0[e] = (short)h0;
        Al0[e] = (short)bf_hi(p0 - from_bf(h0));
        float p1 = bh1 * tl[e];
        unsigned short h1 = bf_hi(p1);
        Ah1[e] = (short)h1;
        Al1[e] = (short)bf_hi(p1 - from_bf(h1));
    }

    const bf16x8* Ub = reinterpret_cast<const bf16x8*>(Ubf);

    f32x4 accre[4], accim[4];
    #pragma unroll
    for (int t = 0; t < 4; ++t) { accre[t] = (f32x4)0.0f; accim[t] = (f32x4)0.0f; }

    #pragma unroll
    for (int t = 0; t < 4; ++t) {
        bf16x8 B0h = Ub[(((0 * 4 + t) * 2 + 0) * 2 + 0) * 64 + lane];
        bf16x8 B0l = Ub[(((0 * 4 + t) * 2 + 0) * 2 + 1) * 64 + lane];
        bf16x8 B1h = Ub[(((0 * 4 + t) * 2 + 1) * 2 + 0) * 64 + lane];
        bf16x8 B1l = Ub[(((0 * 4 + t) * 2 + 1) * 2 + 1) * 64 + lane];
        accre[t] = __builtin_amdgcn_mfma_f32_16x16x32_bf16(Ah0, B0h, accre[t], 0, 0, 0);
        accre[t] = __builtin_amdgcn_mfma_f32_16x16x32_bf16(Al0, B0h, accre[t], 0, 0, 0);
        accre[t] = __builtin_amdgcn_mfma_f32_16x16x32_bf16(Ah0, B0l, accre[t], 0, 0, 0);
        accre[t] = __builtin_amdgcn_mfma_f32_16x16x32_bf16(Ah1, B1h, accre[t], 0, 0, 0);
        accre[t] = __builtin_amdgcn_mfma_f32_16x16x32_bf16(Al1, B1h, accre[t], 0, 0, 0);
        accre[t] = __builtin_amdgcn_mfma_f32_16x16x32_bf16(Ah1, B1l, accre[t], 0, 0, 0);
    }
    #pragma unroll
    for (int t = 0; t < 4; ++t) {
        bf16x8 B0h = Ub[(((1 * 4 + t) * 2 + 0) * 2 + 0) * 64 + lane];
        bf16x8 B0l = Ub[(((1 * 4 + t) * 2 + 0) * 2 + 1) * 64 + lane];
        bf16x8 B1h = Ub[(((1 * 4 + t) * 2 + 1) * 2 + 0) * 64 + lane];
        bf16x8 B1l = Ub[(((1 * 4 + t) * 2 + 1) * 2 + 1) * 64 + lane];
        accim[t] = __builtin_amdgcn_mfma_f32_16x16x32_bf16(Ah0, B0h, accim[t], 0, 0, 0);
        accim[t] = __builtin_amdgcn_mfma_f32_16x16x32_bf16(Al0, B0h, accim[t], 0, 0, 0);
        accim[t] = __builtin_amdgcn_mfma_f32_16x16x32_bf16(Ah0, B0l, accim[t], 0, 0, 0);
        accim[t] = __builtin_amdgcn_mfma_f32_16x16x32_bf16(Ah1, B1h, accim[t], 0, 0, 0);
        accim[t] = __builtin_amdgcn_mfma_f32_16x16x32_bf16(Al1, B1h, accim[t], 0, 0, 0);
        accim[t] = __builtin_amdgcn_mfma_f32_16x16x32_bf16(Ah1, B1l, accim[t], 0, 0, 0);
    }

    #pragma unroll
    for (int r = 0; r < 4; ++r) {
        float p0 = accre[0][r] * accre[0][r] + accim[0][r] * accim[0][r];
        float p1 = accre[1][r] * accre[1][r] + accim[1][r] * accim[1][r];
        float p2 = accre[2][r] * accre[2][r] + accim[2][r] * accim[2][r];
        float p3 = accre[3][r] * accre[3][r] + accim[3][r] * accim[3][r];

        float P0 = p0 + p1 + p2 + p3;
        float P1 = p0 + p1 - p2 - p3;
        float P2 = p0 - p1 + p2 - p3;

        float v = P0;
        #pragma unroll
        for (int st = 0; st < 4; ++st) {
            const int m = 1 << st;
            float prt = __shfl_xor(v, m);
            v = (lane & m) ? (prt - v) : (prt + v);
        }
        #pragma unroll
        for (int st = 0; st < 4; ++st) P1 += __shfl_xor(P1, 1 << st);
        #pragma unroll
        for (int st = 0; st < 4; ++st) P2 += __shfl_xor(P2, 1 << st);

        const int sl = wv * 16 + g * 4 + r;
        if (c == 0) { qlds[sl][0] = P1; qlds[sl][1] = P2; }
        if (c == 8) qlds[sl][2] = v;
        if (c == 4) qlds[sl][3] = v;
        if (c == 2) qlds[sl][4] = v;
        if (c == 1) qlds[sl][5] = v;
    }

    __syncthreads();

    if (tid < 64) {
        const int so = (int)(blk + tid);
        if (so < B) {
            float qv[6];
            #pragma unroll
            for (int i = 0; i < 6; ++i) qv[i] = qlds[tid][i];

            float h4[16];
            #pragma unroll
            for (int o = 0; o < 16; ++o) h4[o] = b4[o];
            #pragma unroll
            for (int q = 0; q < 6; ++q) {
                #pragma unroll
                for (int o = 0; o < 16; ++o) h4[o] = fmaf(qv[q], W4[q * 16 + o], h4[o]);
            }
            #pragma unroll
            for (int o = 0; o < 16; ++o) h4[o] = fmaxf(h4[o], 0.0f);

            float o5[20];
            #pragma unroll
            for (int o = 0; o < 20; ++o) {
                float t = b5[o];
                #pragma unroll
                for (int j = 0; j < 16; ++j) t = fmaf(h4[j], W5[j * 20 + o], t);
                o5[o] = t;
            }

            f32x4* outv = reinterpret_cast<f32x4*>(out + (size_t)so * 20);
            #pragma unroll
            for (int i = 0; i < 5; ++i) {
                f32x4 v = {o5[4 * i], o5[4 * i + 1], o5[4 * i + 2], o5[4 * i + 3]};
                __builtin_nontemporal_store(v, &outv[i]);
            }
        }
    }
}

// ---------------------------------------------------------------------------
extern "C" void kernel_launch(void* const* d_in, const int* in_sizes, int n_in,
                              void* d_out, int out_size, void* d_ws, size_t ws_size,
                              hipStream_t stream) {
    const float* x  = (const float*)d_in[0];
    const float* W1 = (const float*)d_in[1];
    const float* b1 = (const float*)d_in[2];
    const float* W2 = (const float*)d_in[3];
    const float* b2 = (const float*)d_in[4];
    const float* W3 = (const float*)d_in[5];
    const float* b3 = (const float*)d_in[6];
    const float* qw = (const float*)d_in[7];
    const float* W4 = (const float*)d_in[8];
    const float* b4 = (const float*)d_in[9];
    const float* W5 = (const float*)d_in[10];
    const float* b5 = (const float*)d_in[11];
    float* out = (float*)d_out;

    const int B = in_sizes[0] / 128;

    float* Umat = (float*)d_ws;                                     // 8192 floats
    unsigned short* Ubf  = (unsigned short*)((float*)d_ws + 8192);  // 16384 ushort
    unsigned short* W1bf = (unsigned short*)((float*)d_ws + 16384); // 8192 ushort
    float* tab  = (float*)d_ws + 20480;                             // 16*B floats

    build_u<<<64, 64, 0, stream>>>(qw, Umat);
    convert_all<<<1, 64, 0, stream>>>(Umat, W1, Ubf, W1bf);
    front_mfma<<<(B + 255) / 256, 256, 0, stream>>>(
        x, W1bf, b1, W2, b2, W3, b3, tab, B);
    gemv_mfma<<<(B + 63) / 64, 256, 0, stream>>>(
        tab, Ubf, W4, b4, W5, b5, out, B);
}

// Round 23
// 94.237 us; speedup vs baseline: 1.3447x; 1.0328x over previous
//
#include <hip/hip_runtime.h>
#include <hip/hip_bf16.h>
#include <math.h>

#define PI_F 3.14159265358979323846f

typedef float f32x4 __attribute__((ext_vector_type(4)));
typedef short bf16x8 __attribute__((ext_vector_type(8)));

__device__ __forceinline__ unsigned short bf_hi(float f) {
    return (unsigned short)(__float_as_uint(f) >> 16);     // truncate to bf16
}
__device__ __forceinline__ float from_bf(unsigned short h) {
    return __uint_as_float(((unsigned)h) << 16);
}

// ---------------------------------------------------------------------------
// Kernel 1: build the fixed 64x64 complex unitary U. K-MAJOR layout:
// Umat[k*128 + j*2 + {0,1}] = {Re,Im} of U[k][j]. 64 parallel blocks.
// ---------------------------------------------------------------------------
__global__ __launch_bounds__(64) void build_u(const float* __restrict__ qw,
                                              float* __restrict__ Umat) {
    const int l = threadIdx.x;   // amplitude index k (0..63)
    const int b = blockIdx.x;    // input basis state j (0..63)

    float ar = (l == b) ? 1.0f : 0.0f;
    float ai = 0.0f;

    #pragma unroll
    for (int i = 0; i < 6; ++i) {
        const int mask = 1 << (5 - i);
        float th = 0.5f * qw[0 * 6 + i];
        float c = cosf(th), sn = sinf(th);
        float pr = __shfl_xor(ar, mask);
        float pi = __shfl_xor(ai, mask);
        float nr = c * ar + sn * pi;
        float ni = c * ai - sn * pr;
        ar = nr; ai = ni;
        th = 0.5f * qw[1 * 6 + i];
        c = cosf(th); sn = sinf(th);
        float zn = (l & mask) ? 1.0f : -1.0f;
        nr = c * ar - zn * sn * ai;
        ni = c * ai + zn * sn * ar;
        ar = nr; ai = ni;
    }

    #pragma unroll
    for (int i = 0; i < 6; ++i) {
        const int ctrl = i, tgt = (i + 1) % 6;
        const int cm = 1 << (5 - ctrl), tm = 1 << (5 - tgt);
        float pr = __shfl_xor(ar, tm);
        float pi = __shfl_xor(ai, tm);
        bool take = (l & cm) != 0;
        ar = take ? pr : ar;
        ai = take ? pi : ai;
    }

    #pragma unroll
    for (int i = 0; i < 6; ++i) {
        const int mask = 1 << (5 - i);
        float th = 0.5f * qw[2 * 6 + i];
        float c = cosf(th), sn = sinf(th);
        float pr = __shfl_xor(ar, mask);
        float pi = __shfl_xor(ai, mask);
        float sg = (l & mask) ? sn : -sn;
        float nr = c * ar + sg * pr;
        float ni = c * ai + sg * pi;
        ar = nr; ai = ni;
        th = 0.5f * qw[3 * 6 + i];
        c = cosf(th); sn = sinf(th);
        float zn = (l & mask) ? 1.0f : -1.0f;
        nr = c * ar - zn * sn * ai;
        ni = c * ai + zn * sn * ar;
        ar = nr; ai = ni;
    }

    #pragma unroll
    for (int i = 0; i < 6; i += 2) {
        const int cm = 1 << (5 - i), tm = 1 << (5 - (i + 1));
        float pr = __shfl_xor(ar, tm);
        float pi = __shfl_xor(ai, tm);
        bool take = (l & cm) != 0;
        ar = take ? pr : ar;
        ai = take ? pi : ai;
    }

    #pragma unroll
    for (int i = 0; i < 6; ++i) {
        const int mask = 1 << (5 - i);
        float th = 0.5f * qw[4 * 6 + i];
        float c = cosf(th), sn = sinf(th);
        float pr = __shfl_xor(ar, mask);
        float pi = __shfl_xor(ai, mask);
        float nr = c * ar + sn * pi;
        float ni = c * ai - sn * pr;
        ar = nr; ai = ni;
    }

    Umat[(l * 64 + b) * 2 + 0] = ar;   // k-major: row k=l, col j=b
    Umat[(l * 64 + b) * 2 + 1] = ai;
}

// ---------------------------------------------------------------------------
// Kernel 1b: pack U and W1 into split-bf16 MFMA B-fragment layout
// (both verified: U in R17, W1 in R18).
// ---------------------------------------------------------------------------
__global__ __launch_bounds__(64) void convert_all(
    const float* __restrict__ Umat, const float* __restrict__ W1,
    unsigned short* __restrict__ Ubf, unsigned short* __restrict__ W1bf)
{
    const int l = threadIdx.x;
    bf16x8* out8 = reinterpret_cast<bf16x8*>(Ubf);

    #pragma unroll
    for (int ri = 0; ri < 2; ++ri) {
        #pragma unroll
        for (int t = 0; t < 4; ++t) {
            #pragma unroll
            for (int h = 0; h < 2; ++h) {
                const int vf = (ri * 4 + t) * 2 + h;
                bf16x8 vh, vl;
                #pragma unroll
                for (int e = 0; e < 8; ++e) {
                    const int k = 16 * t + (l & 15);
                    const int j = h * 32 + (l >> 4) * 8 + e;
                    float v = Umat[k * 128 + j * 2 + ri];
                    unsigned short hh = bf_hi(v);
                    vh[e] = (short)hh;
                    vl[e] = (short)bf_hi(v - from_bf(hh));
                }
                out8[(vf * 2 + 0) * 64 + l] = vh;
                out8[(vf * 2 + 1) * 64 + l] = vl;
            }
        }
    }

    bf16x8* w8 = reinterpret_cast<bf16x8*>(W1bf);
    #pragma unroll
    for (int ks = 0; ks < 4; ++ks) {
        #pragma unroll
        for (int nt = 0; nt < 2; ++nt) {
            bf16x8 vh, vl;
            #pragma unroll
            for (int e = 0; e < 8; ++e) {
                float v = W1[(ks * 32 + (l >> 4) * 8 + e) * 32 + nt * 16 + (l & 15)];
                unsigned short hh = bf_hi(v);
                vh[e] = (short)hh;
                vl[e] = (short)bf_hi(v - from_bf(hh));
            }
            w8[((ks * 2 + nt) * 2 + 0) * 64 + l] = vh;
            w8[((ks * 2 + nt) * 2 + 1) * 64 + l] = vl;
        }
    }
}

// ---------------------------------------------------------------------------
// Front MLP tail (layers 2,3 + half-product tables). Verified since R3.
// ---------------------------------------------------------------------------
__device__ __forceinline__ void front_tail(
    const float h1[32],
    const float* __restrict__ W2, const float* __restrict__ b2,
    const float* __restrict__ W3, const float* __restrict__ b3,
    float lo[8], float hi[8])
{
    float h2[16];
    #pragma unroll
    for (int o = 0; o < 16; ++o) h2[o] = b2[o];
    #pragma unroll
    for (int j = 0; j < 32; ++j) {
        #pragma unroll
        for (int o = 0; o < 16; ++o) h2[o] = fmaf(h1[j], W2[j * 16 + o], h2[o]);
    }
    #pragma unroll
    for (int o = 0; o < 16; ++o) h2[o] = fmaxf(h2[o], 0.0f);

    float cq[6], sq[6];
    #pragma unroll
    for (int q = 0; q < 6; ++q) {
        float t = b3[q];
        #pragma unroll
        for (int j = 0; j < 16; ++j) t = fmaf(h2[j], W3[j * 6 + q], t);
        t = tanhf(t);
        t = fminf(1.0f, fmaxf(-1.0f, t));
        float half = t * (0.5f * PI_F);
        sq[q] = sinf(half);
        cq[q] = cosf(half);
    }

    {
        float f3[2] = {cq[3], sq[3]};
        float f4[2] = {cq[4], sq[4]};
        float f5[2] = {cq[5], sq[5]};
        #pragma unroll
        for (int m = 0; m < 8; ++m)
            lo[m] = f3[(m >> 2) & 1] * f4[(m >> 1) & 1] * f5[m & 1];
        float f0[2] = {cq[0], sq[0]};
        float f1[2] = {cq[1], sq[1]};
        float f2[2] = {cq[2], sq[2]};
        #pragma unroll
        for (int m = 0; m < 8; ++m)
            hi[m] = f0[(m >> 2) & 1] * f1[(m >> 1) & 1] * f2[m & 1];
    }
}

// ---------------------------------------------------------------------------
// Split kernel A: front MLP, MFMA + coalesced LDS staging.
// R23 change: 128 samples per 256-thread block (was 256). LDS 36->18 KB,
// so blocks/CU rises 4->8 and waves/CU 16->32 (full occupancy) -- the
// kernel is latency-bound, so TLP is the binding resource. Per-wave MFMA
// work halves (2 mt tiles); tail runs on threads 0..127 (1 sample/thread,
// same per-thread cost; waves 2-3 exit).
// ---------------------------------------------------------------------------
__global__ __launch_bounds__(256) void front_mfma(
    const float* __restrict__ x,
    const unsigned short* __restrict__ W1bf, const float* __restrict__ b1,
    const float* __restrict__ W2, const float* __restrict__ b2,
    const float* __restrict__ W3, const float* __restrict__ b3,
    float* __restrict__ tab, int B)
{
    __shared__ float smem[128 * 36];         // 18432 B -> 8 blocks/CU

    const int tid  = threadIdx.x;
    const int wv   = tid >> 6;
    const int lane = tid & 63;
    const int g    = lane >> 4;
    const int c    = lane & 15;
    const long blk = (long)blockIdx.x * 128;

    const f32x4* xg = reinterpret_cast<const f32x4*>(x);
    const bf16x8* Wb = reinterpret_cast<const bf16x8*>(W1bf);

    f32x4 acc0[2], acc1[2];
    #pragma unroll
    for (int mt = 0; mt < 2; ++mt) { acc0[mt] = (f32x4)0.0f; acc1[mt] = (f32x4)0.0f; }

    #pragma unroll 1
    for (int ks = 0; ks < 4; ++ks) {
        // ---- coalesced NT stage: 128 rows x 8 f32x4 = 1024 -> 4 per thread
        #pragma unroll
        for (int i = 0; i < 4; ++i) {
            const int flat = i * 256 + tid;
            const int row = flat >> 3;        // 0..127
            const int c4  = flat & 7;         // 0..7
            long srow = blk + row;
            if (srow >= B) srow = B - 1;
            f32x4 v = __builtin_nontemporal_load(&xg[(size_t)srow * 32 + ks * 8 + c4]);
            *reinterpret_cast<f32x4*>(&smem[row * 36 + c4 * 4]) = v;
        }
        __syncthreads();

        bf16x8 B0h = Wb[((ks * 2 + 0) * 2 + 0) * 64 + lane];
        bf16x8 B0l = Wb[((ks * 2 + 0) * 2 + 1) * 64 + lane];
        bf16x8 B1h = Wb[((ks * 2 + 1) * 2 + 0) * 64 + lane];
        bf16x8 B1l = Wb[((ks * 2 + 1) * 2 + 1) * 64 + lane];

        #pragma unroll
        for (int mt = 0; mt < 2; ++mt) {
            const int row = wv * 32 + mt * 16 + c;       // sample (local, 0..127)
            f32x4 xa = *reinterpret_cast<const f32x4*>(&smem[row * 36 + g * 8]);
            f32x4 xb = *reinterpret_cast<const f32x4*>(&smem[row * 36 + g * 8 + 4]);

            bf16x8 Ah, Al;
            #pragma unroll
            for (int e = 0; e < 4; ++e) {
                unsigned short hh = bf_hi(xa[e]);
                Ah[e] = (short)hh;
                Al[e] = (short)bf_hi(xa[e] - from_bf(hh));
            }
            #pragma unroll
            for (int e = 0; e < 4; ++e) {
                unsigned short hh = bf_hi(xb[e]);
                Ah[4 + e] = (short)hh;
                Al[4 + e] = (short)bf_hi(xb[e] - from_bf(hh));
            }

            acc0[mt] = __builtin_amdgcn_mfma_f32_16x16x32_bf16(Ah, B0h, acc0[mt], 0, 0, 0);
            acc0[mt] = __builtin_amdgcn_mfma_f32_16x16x32_bf16(Al, B0h, acc0[mt], 0, 0, 0);
            acc0[mt] = __builtin_amdgcn_mfma_f32_16x16x32_bf16(Ah, B0l, acc0[mt], 0, 0, 0);
            acc1[mt] = __builtin_amdgcn_mfma_f32_16x16x32_bf16(Ah, B1h, acc1[mt], 0, 0, 0);
            acc1[mt] = __builtin_amdgcn_mfma_f32_16x16x32_bf16(Al, B1h, acc1[mt], 0, 0, 0);
            acc1[mt] = __builtin_amdgcn_mfma_f32_16x16x32_bf16(Ah, B1l, acc1[mt], 0, 0, 0);
        }
        __syncthreads();
    }

    // ---- D -> LDS at stride 33 (reuse smem; 127*33+31 = 4222 < 4608)
    #pragma unroll
    for (int mt = 0; mt < 2; ++mt) {
        #pragma unroll
        for (int r = 0; r < 4; ++r) {
            smem[(wv * 32 + mt * 16 + g * 4 + r) * 33 + c]      = acc0[mt][r];
            smem[(wv * 32 + mt * 16 + g * 4 + r) * 33 + 16 + c] = acc1[mt][r];
        }
    }

    __syncthreads();

    // ---- tail: threads 0..127, one sample each (waves 2-3 exit)
    if (tid < 128) {
        const int s = (int)(blk + tid);
        float h1[32];
        #pragma unroll
        for (int o = 0; o < 32; ++o) h1[o] = fmaxf(smem[tid * 33 + o] + b1[o], 0.0f);

        float lo[8], hi[8];
        front_tail(h1, W2, b2, W3, b3, lo, hi);

        if (s < B) {
            #pragma unroll
            for (int i = 0; i < 8; ++i)
                __builtin_nontemporal_store(lo[i], &tab[(size_t)i * B + s]);
            #pragma unroll
            for (int i = 0; i < 8; ++i)
                __builtin_nontemporal_store(hi[i], &tab[(size_t)(8 + i) * B + s]);
        }
    }
}

// ---------------------------------------------------------------------------
// Split kernel B (R17/R18/R20, verified): straight-line MFMA GEMV, 64
// samples/block, epilogue + back MLP on threads 0..63 (waves 1-3 exit).
// ---------------------------------------------------------------------------
__global__ __launch_bounds__(256) void gemv_mfma(
    const float* __restrict__ tab,
    const unsigned short* __restrict__ Ubf,
    const float* __restrict__ W4, const float* __restrict__ b4,
    const float* __restrict__ W5, const float* __restrict__ b5,
    float* __restrict__ out, int B)
{
    __shared__ float qlds[64][8];

    const int tid  = threadIdx.x;
    const int wv   = tid >> 6;
    const int lane = tid & 63;
    const int g    = lane >> 4;
    const int c    = lane & 15;
    const long blk = (long)blockIdx.x * 64;
    const int s    = (int)(blk + wv * 16 + c);
    const int s_ld = (s < B) ? s : (B - 1);

    float tl[8], th[8];
    #pragma unroll
    for (int i = 0; i < 8; ++i)
        tl[i] = __builtin_nontemporal_load(&tab[(size_t)i * B + s_ld]);
    #pragma unroll
    for (int i = 0; i < 8; ++i)
        th[i] = __builtin_nontemporal_load(&tab[(size_t)(8 + i) * B + s_ld]);

    float bh0 = (g == 0) ? th[0] : (g == 1) ? th[1] : (g == 2) ? th[2] : th[3];
    float bh1 = (g == 0) ? th[4] : (g == 1) ? th[5] : (g == 2) ? th[6] : th[7];

    bf16x8 Ah0, Al0, Ah1, Al1;
    #pragma unroll
    for (int e = 0; e < 8; ++e) {
        float p0 = bh0 * tl[e];
        unsigned short h0 = bf_hi(p0);
        Ah0[e] = (short)h0;
        Al0[e] = (short)bf_hi(p0 - from_bf(h0));
        float p1 = bh1 * tl[e];
        unsigned short h1 = bf_hi(p1);
        Ah1[e] = (short)h1;
        Al1[e] = (short)bf_hi(p1 - from_bf(h1));
    }

    const bf16x8* Ub = reinterpret_cast<const bf16x8*>(Ubf);

    f32x4 accre[4], accim[4];
    #pragma unroll
    for (int t = 0; t < 4; ++t) { accre[t] = (f32x4)0.0f; accim[t] = (f32x4)0.0f; }

    #pragma unroll
    for (int t = 0; t < 4; ++t) {
        bf16x8 B0h = Ub[(((0 * 4 + t) * 2 + 0) * 2 + 0) * 64 + lane];
        bf16x8 B0l = Ub[(((0 * 4 + t) * 2 + 0) * 2 + 1) * 64 + lane];
        bf16x8 B1h = Ub[(((0 * 4 + t) * 2 + 1) * 2 + 0) * 64 + lane];
        bf16x8 B1l = Ub[(((0 * 4 + t) * 2 + 1) * 2 + 1) * 64 + lane];
        accre[t] = __builtin_amdgcn_mfma_f32_16x16x32_bf16(Ah0, B0h, accre[t], 0, 0, 0);
        accre[t] = __builtin_amdgcn_mfma_f32_16x16x32_bf16(Al0, B0h, accre[t], 0, 0, 0);
        accre[t] = __builtin_amdgcn_mfma_f32_16x16x32_bf16(Ah0, B0l, accre[t], 0, 0, 0);
        accre[t] = __builtin_amdgcn_mfma_f32_16x16x32_bf16(Ah1, B1h, accre[t], 0, 0, 0);
        accre[t] = __builtin_amdgcn_mfma_f32_16x16x32_bf16(Al1, B1h, accre[t], 0, 0, 0);
        accre[t] = __builtin_amdgcn_mfma_f32_16x16x32_bf16(Ah1, B1l, accre[t], 0, 0, 0);
    }
    #pragma unroll
    for (int t = 0; t < 4; ++t) {
        bf16x8 B0h = Ub[(((1 * 4 + t) * 2 + 0) * 2 + 0) * 64 + lane];
        bf16x8 B0l = Ub[(((1 * 4 + t) * 2 + 0) * 2 + 1) * 64 + lane];
        bf16x8 B1h = Ub[(((1 * 4 + t) * 2 + 1) * 2 + 0) * 64 + lane];
        bf16x8 B1l = Ub[(((1 * 4 + t) * 2 + 1) * 2 + 1) * 64 + lane];
        accim[t] = __builtin_amdgcn_mfma_f32_16x16x32_bf16(Ah0, B0h, accim[t], 0, 0, 0);
        accim[t] = __builtin_amdgcn_mfma_f32_16x16x32_bf16(Al0, B0h, accim[t], 0, 0, 0);
        accim[t] = __builtin_amdgcn_mfma_f32_16x16x32_bf16(Ah0, B0l, accim[t], 0, 0, 0);
        accim[t] = __builtin_amdgcn_mfma_f32_16x16x32_bf16(Ah1, B1h, accim[t], 0, 0, 0);
        accim[t] = __builtin_amdgcn_mfma_f32_16x16x32_bf16(Al1, B1h, accim[t], 0, 0, 0);
        accim[t] = __builtin_amdgcn_mfma_f32_16x16x32_bf16(Ah1, B1l, accim[t], 0, 0, 0);
    }

    #pragma unroll
    for (int r = 0; r < 4; ++r) {
        float p0 = accre[0][r] * accre[0][r] + accim[0][r] * accim[0][r];
        float p1 = accre[1][r] * accre[1][r] + accim[1][r] * accim[1][r];
        float p2 = accre[2][r] * accre[2][r] + accim[2][r] * accim[2][r];
        float p3 = accre[3][r] * accre[3][r] + accim[3][r] * accim[3][r];

        float P0 = p0 + p1 + p2 + p3;
        float P1 = p0 + p1 - p2 - p3;
        float P2 = p0 - p1 + p2 - p3;

        float v = P0;
        #pragma unroll
        for (int st = 0; st < 4; ++st) {
            const int m = 1 << st;
            float prt = __shfl_xor(v, m);
            v = (lane & m) ? (prt - v) : (prt + v);
        }
        #pragma unroll
        for (int st = 0; st < 4; ++st) P1 += __shfl_xor(P1, 1 << st);
        #pragma unroll
        for (int st = 0; st < 4; ++st) P2 += __shfl_xor(P2, 1 << st);

        const int sl = wv * 16 + g * 4 + r;
        if (c == 0) { qlds[sl][0] = P1; qlds[sl][1] = P2; }
        if (c == 8) qlds[sl][2] = v;
        if (c == 4) qlds[sl][3] = v;
        if (c == 2) qlds[sl][4] = v;
        if (c == 1) qlds[sl][5] = v;
    }

    __syncthreads();

    if (tid < 64) {
        const int so = (int)(blk + tid);
        if (so < B) {
            float qv[6];
            #pragma unroll
            for (int i = 0; i < 6; ++i) qv[i] = qlds[tid][i];

            float h4[16];
            #pragma unroll
            for (int o = 0; o < 16; ++o) h4[o] = b4[o];
            #pragma unroll
            for (int q = 0; q < 6; ++q) {
                #pragma unroll
                for (int o = 0; o < 16; ++o) h4[o] = fmaf(qv[q], W4[q * 16 + o], h4[o]);
            }
            #pragma unroll
            for (int o = 0; o < 16; ++o) h4[o] = fmaxf(h4[o], 0.0f);

            float o5[20];
            #pragma unroll
            for (int o = 0; o < 20; ++o) {
                float t = b5[o];
                #pragma unroll
                for (int j = 0; j < 16; ++j) t = fmaf(h4[j], W5[j * 20 + o], t);
                o5[o] = t;
            }

            f32x4* outv = reinterpret_cast<f32x4*>(out + (size_t)so * 20);
            #pragma unroll
            for (int i = 0; i < 5; ++i) {
                f32x4 v = {o5[4 * i], o5[4 * i + 1], o5[4 * i + 2], o5[4 * i + 3]};
                __builtin_nontemporal_store(v, &outv[i]);
            }
        }
    }
}

// ---------------------------------------------------------------------------
extern "C" void kernel_launch(void* const* d_in, const int* in_sizes, int n_in,
                              void* d_out, int out_size, void* d_ws, size_t ws_size,
                              hipStream_t stream) {
    const float* x  = (const float*)d_in[0];
    const float* W1 = (const float*)d_in[1];
    const float* b1 = (const float*)d_in[2];
    const float* W2 = (const float*)d_in[3];
    const float* b2 = (const float*)d_in[4];
    const float* W3 = (const float*)d_in[5];
    const float* b3 = (const float*)d_in[6];
    const float* qw = (const float*)d_in[7];
    const float* W4 = (const float*)d_in[8];
    const float* b4 = (const float*)d_in[9];
    const float* W5 = (const float*)d_in[10];
    const float* b5 = (const float*)d_in[11];
    float* out = (float*)d_out;

    const int B = in_sizes[0] / 128;

    float* Umat = (float*)d_ws;                                     // 8192 floats
    unsigned short* Ubf  = (unsigned short*)((float*)d_ws + 8192);  // 16384 ushort
    unsigned short* W1bf = (unsigned short*)((float*)d_ws + 16384); // 8192 ushort
    float* tab  = (float*)d_ws + 20480;                             // 16*B floats

    build_u<<<64, 64, 0, stream>>>(qw, Umat);
    convert_all<<<1, 64, 0, stream>>>(Umat, W1, Ubf, W1bf);
    front_mfma<<<(B + 127) / 128, 256, 0, stream>>>(
        x, W1bf, b1, W2, b2, W3, b3, tab, B);
    gemv_mfma<<<(B + 63) / 64, 256, 0, stream>>>(
        tab, Ubf, W4, b4, W5, b5, out, B);
}